// Round 7
// baseline (385.765 us; speedup 1.0000x reference)
//
#include <hip/hip_runtime.h>

typedef __attribute__((ext_vector_type(8))) short bf16x8;
typedef __attribute__((ext_vector_type(4))) float f32x4;

#define HID 50
#define TSTEPS 512
#define LOG2E 1.4426950408889634f

static __device__ __forceinline__ short f2bf(float f) {
    unsigned u = __builtin_bit_cast(unsigned, f);
    u = (u + 0x7fffu + ((u >> 16) & 1u)) >> 16;   // RNE
    return (short)u;
}

static __device__ __forceinline__ float fexp2(float x) {
#if __has_builtin(__builtin_amdgcn_exp2f)
    return __builtin_amdgcn_exp2f(x);
#else
    return exp2f(x);
#endif
}
static __device__ __forceinline__ float frcp(float x) {
#if __has_builtin(__builtin_amdgcn_rcpf)
    return __builtin_amdgcn_rcpf(x);
#else
    return 1.0f / x;
#endif
}
static __device__ __forceinline__ float sigm(float x) {
    return frcp(1.0f + fexp2(-LOG2E * x));
}
static __device__ __forceinline__ float tanh_(float x) {
    return 1.0f - 2.0f * frcp(1.0f + fexp2(2.0f * LOG2E * x));
}

// LDS-write-only barrier: drain lgkmcnt (ds_writes) but leave global x-prefetch
// loads in flight. sched_barrier(0) per rule 18.
static __device__ __forceinline__ void lds_barrier() {
    asm volatile("s_waitcnt lgkmcnt(0)" ::: "memory");
    __builtin_amdgcn_sched_barrier(0);
    __builtin_amdgcn_s_barrier();
}

// R7: 8 waves/block (512 thr) = 2 waves/SIMD for latency interleave.
// Waves pair on a j-slice: jg = wv>>1 in 0..3 owns hidden cols [jg*16,jg*16+16).
// Both waves of a pair run identical {LDS A-read, x-inject, 8 MFMA} (matrix pipe
// is ~10% busy; duplication is free), then SPLIT the activation work by
// accumulator row: even wave handles acc rows 0,1; odd wave rows 2,3.
// Chip-wide VALU issue is conserved, per-wave issue halves, and the two waves
// on a SIMD fill each other's trans/LDS latency stalls.
//
// Gate pre-activation is ONE K=64 MFMA pair:
//   A row b = [ h[b][0..49] | x[b][t][0..3] | 1.0 | 0.. ]
//   B col j = [ W_hh[g][j][:] | W_ih[g][j][:] | bias_g[j] | 0.. ]  (VGPR-resident)
__global__ __launch_bounds__(512) void lstm_fused(
    const float* __restrict__ seq,
    const float* __restrict__ W_ih,
    const float* __restrict__ W_hh,
    const float* __restrict__ b_ih,
    const float* __restrict__ b_hh,
    const float* __restrict__ W_out,
    const float* __restrict__ b_out,
    float* __restrict__ out)
{
    __shared__ __align__(16) short h_lds[2 * 16 * 64];  // bf16 bits, dbuf, XOR-swizzled rows of 128B
    __shared__ float h32[16][51];                       // final h staging

    const int tid  = threadIdx.x;
    const int l    = tid & 63;
    const int wv   = tid >> 6;         // 0..7
    const int jg   = wv >> 1;          // j-slice 0..3
    const bool rodd = (wv & 1) != 0;   // acc rows {2,3} vs {0,1}
    const int rp   = rodd ? 2 : 0;
    const int l15  = l & 15;
    const int lq   = l >> 4;           // 0..3
    const int jl   = jg * 16 + l15;    // padded hidden col 0..63
    const bool jv  = (jl < HID);
    const int rowbase = blockIdx.x << 4;
    const int swz = (l15 & 7) << 4;    // A-read swizzle (row = l15)

    for (int i = tid; i < 2 * 16 * 64; i += 512) h_lds[i] = 0;

    // ---- B fragments: [W_hh^T | W_ih^T | bias], bf16, VGPR-resident all 512 steps.
    bf16x8 Bf[4][2];
#pragma unroll
    for (int g = 0; g < 4; ++g)
#pragma unroll
        for (int kk = 0; kk < 2; ++kk) {
            bf16x8 v;
#pragma unroll
            for (int e = 0; e < 8; ++e) {
                int k = kk * 32 + lq * 8 + e;
                float val = 0.0f;
                if (jv) {
                    if (k < HID)            val = W_hh[(g * HID + jl) * HID + k];
                    else if (k < HID + 4)   val = W_ih[(g * HID + jl) * 4 + (k - HID)];
                    else if (k == HID + 4)  val = b_ih[g * HID + jl] + b_hh[g * HID + jl];
                }
                v[e] = f2bf(val);
            }
            Bf[g][kk] = v;
        }

    // ---- x prefetch: lq==2 lanes feed x (k=48..55 A-slice). Distance-2.
    const char* xp = (const char*)seq + (size_t)(rowbase + l15) * TSTEPS * 16;
    float4 sqA = make_float4(0.f, 0.f, 0.f, 0.f);
    float4 sqB = make_float4(0.f, 0.f, 0.f, 0.f);
    if (lq == 2) {
        sqA = *(const float4*)(xp);
        sqB = *(const float4*)(xp + 16);
    }

    float c0 = 0.f, c1 = 0.f, h0 = 0.f, h1 = 0.f;

    // ---- loop-invariant LDS addresses (dbuf offsets fold into ds imm)
    const char* rdA = (const char*)h_lds + l15 * 128 + ((lq * 16) ^ swz);
    const char* rdB = (const char*)h_lds + l15 * 128 + ((64 + lq * 16) ^ swz);
    const int row0 = lq * 4 + rp, row1 = row0 + 1;
    char* wb0 = (char*)h_lds + row0 * 128 + ((2 * jl) ^ ((row0 & 7) << 4));
    char* wb1 = (char*)h_lds + row1 * 128 + ((2 * jl) ^ ((row1 & 7) << 4));

    __syncthreads();   // h_lds zeroed

    // One step: read A(prev h) -> inject x/1.0 -> issue t+2 prefetch -> 8 MFMA ->
    // select my 2 acc rows (wave-uniform branch, static indices) -> activations ->
    // write my 2 h values -> lgkm-only barrier.
#define STEP(TT, SQ, RDOFF, WROFF)                                                             \
    {                                                                                          \
        bf16x8 a0 = *(const bf16x8*)(rdA + (RDOFF));                                           \
        bf16x8 a1 = *(const bf16x8*)(rdB + (RDOFF));                                           \
        if (lq == 2) {                                                                         \
            a1[2] = f2bf(SQ.x); a1[3] = f2bf(SQ.y);                                            \
            a1[4] = f2bf(SQ.z); a1[5] = f2bf(SQ.w);                                            \
            a1[6] = (short)0x3f80;  /* 1.0 -> bias row */                                      \
        }                                                                                      \
        if ((TT) + 2 < TSTEPS && lq == 2)                                                      \
            SQ = *(const float4*)(xp + ((TT) + 2) * 16);                                       \
        f32x4 ac0 = {0.f,0.f,0.f,0.f}, ac1 = {0.f,0.f,0.f,0.f};                                \
        f32x4 ac2 = {0.f,0.f,0.f,0.f}, ac3 = {0.f,0.f,0.f,0.f};                                \
        ac0 = __builtin_amdgcn_mfma_f32_16x16x32_bf16(a0, Bf[0][0], ac0, 0, 0, 0);             \
        ac1 = __builtin_amdgcn_mfma_f32_16x16x32_bf16(a0, Bf[1][0], ac1, 0, 0, 0);             \
        ac2 = __builtin_amdgcn_mfma_f32_16x16x32_bf16(a0, Bf[2][0], ac2, 0, 0, 0);             \
        ac3 = __builtin_amdgcn_mfma_f32_16x16x32_bf16(a0, Bf[3][0], ac3, 0, 0, 0);             \
        ac0 = __builtin_amdgcn_mfma_f32_16x16x32_bf16(a1, Bf[0][1], ac0, 0, 0, 0);             \
        ac1 = __builtin_amdgcn_mfma_f32_16x16x32_bf16(a1, Bf[1][1], ac1, 0, 0, 0);             \
        ac2 = __builtin_amdgcn_mfma_f32_16x16x32_bf16(a1, Bf[2][1], ac2, 0, 0, 0);             \
        ac3 = __builtin_amdgcn_mfma_f32_16x16x32_bf16(a1, Bf[3][1], ac3, 0, 0, 0);             \
        float zi0, zf0, zg0, zo0, zi1, zf1, zg1, zo1;                                          \
        if (rodd) {                                                                            \
            zi0 = ac0[2]; zf0 = ac1[2]; zg0 = ac2[2]; zo0 = ac3[2];                            \
            zi1 = ac0[3]; zf1 = ac1[3]; zg1 = ac2[3]; zo1 = ac3[3];                            \
        } else {                                                                               \
            zi0 = ac0[0]; zf0 = ac1[0]; zg0 = ac2[0]; zo0 = ac3[0];                            \
            zi1 = ac0[1]; zf1 = ac1[1]; zg1 = ac2[1]; zo1 = ac3[1];                            \
        }                                                                                      \
        {                                                                                      \
            float iv = sigm(zi0), fv = sigm(zf0), gv = tanh_(zg0), ov = sigm(zo0);             \
            c0 = fv * c0 + iv * gv;                                                            \
            h0 = ov * tanh_(c0);                                                               \
        }                                                                                      \
        {                                                                                      \
            float iv = sigm(zi1), fv = sigm(zf1), gv = tanh_(zg1), ov = sigm(zo1);             \
            c1 = fv * c1 + iv * gv;                                                            \
            h1 = ov * tanh_(c1);                                                               \
        }                                                                                      \
        if (jv) {                                                                              \
            *(short*)(wb0 + (WROFF)) = f2bf(h0);                                               \
            *(short*)(wb1 + (WROFF)) = f2bf(h1);                                               \
        }                                                                                      \
        lds_barrier();                                                                         \
    }

    for (int t = 0; t < TSTEPS; t += 2) {
        STEP(t,     sqA, 0,    2048);
        STEP(t + 1, sqB, 2048, 0);
    }
#undef STEP

    // ---- epilogue: out[b] = h_last[b,:] @ W_out + b_out (fp32 h from regs)
    if (jv) {
        h32[row0][jl] = h0;
        h32[row1][jl] = h1;
    }
    __syncthreads();
    if (tid < 16) {
        float s = b_out[0];
        for (int j = 0; j < HID; ++j) s += h32[tid][j] * W_out[j];
        out[rowbase + tid] = s;
    }
}

extern "C" void kernel_launch(void* const* d_in, const int* in_sizes, int n_in,
                              void* d_out, int out_size, void* d_ws, size_t ws_size,
                              hipStream_t stream) {
    const float* seq   = (const float*)d_in[0];
    const float* W_ih  = (const float*)d_in[1];
    const float* W_hh  = (const float*)d_in[2];
    const float* b_ih  = (const float*)d_in[3];
    const float* b_hh  = (const float*)d_in[4];
    const float* W_out = (const float*)d_in[5];
    const float* b_out = (const float*)d_in[6];
    float* out = (float*)d_out;

    const int B = in_sizes[0] / (TSTEPS * 4);   // 4096
    lstm_fused<<<dim3(B / 16), dim3(512), 0, stream>>>(
        seq, W_ih, W_hh, b_ih, b_hh, W_out, b_out, out);
}